// Round 7
// baseline (820.241 us; speedup 1.0000x reference)
//
#include <hip/hip_runtime.h>
#include <stdint.h>

#define D 2048
#define LSEQ 2048
#define BATCH 4
#define BL (BATCH * LSEQ)   // 8192 rows
#define NSLOT 16
#define NHEAD 32
#define HDIM 64
#define EPSV 1e-6f

typedef __attribute__((ext_vector_type(8))) short bf16x8;
typedef __attribute__((ext_vector_type(4))) float f32x4;

static __device__ __forceinline__ ushort f2bf(float f) {
    uint32_t u = __float_as_uint(f);
    u += 0x7fffu + ((u >> 16) & 1u);   // RNE
    return (ushort)(u >> 16);
}

static __device__ __forceinline__ float wave_sum(float v) {
#pragma unroll
    for (int off = 32; off > 0; off >>= 1) v += __shfl_xor(v, off, 64);
    return v;
}

static __device__ __forceinline__ void gl_lds16(const void* g, void* l) {
    __builtin_amdgcn_global_load_lds(
        (__attribute__((address_space(1))) uint32_t*)(uintptr_t)g,
        (__attribute__((address_space(3))) uint32_t*)(uint32_t)(uintptr_t)l,
        16, 0, 0);
}

// ---------------- weight convert f32 -> bf16 ----------------
__global__ __launch_bounds__(256) void conv_bf16_kernel(const float4* __restrict__ src,
                                                        ushort* __restrict__ dst, int n4) {
    int i = blockIdx.x * 256 + threadIdx.x;
    int stride = gridDim.x * 256;
    for (; i < n4; i += stride) {
        float4 v = src[i];
        uint2 o;
        o.x = (uint)f2bf(v.x) | ((uint)f2bf(v.y) << 16);
        o.y = (uint)f2bf(v.z) | ((uint)f2bf(v.w) << 16);
        *(uint2*)(dst + (size_t)i * 4) = o;
    }
}

// ---------------- logits v4: 4 rows/block, BIT-EXACT to the R4-passing kernel ----
// DO NOT change any arithmetic here: logits bits feed top-k (an order-statistic
// discontinuity); R5 failed from a 1e-7-level summation-order change.
__global__ __launch_bounds__(256) void logits_kernel(
    const float* __restrict__ x, const float* __restrict__ cw,
    const float* __restrict__ cb, const float* __restrict__ wpre,
    float* __restrict__ logits_t) {
    int blk = blockIdx.x;              // 2048 blocks, 4 rows each
    int b = blk >> 9;                  // 512 blocks per batch
    int l0 = (blk & 511) << 2;
    int tid = threadIdx.x;
    int i0 = tid * 8;
    float4 w0 = *(const float4*)(wpre + i0);
    float4 w1 = *(const float4*)(wpre + i0 + 4);
    float wv[8] = {w0.x, w0.y, w0.z, w0.w, w1.x, w1.y, w1.z, w1.w};
    float xw[4][8];
    float ss[4];
#pragma unroll
    for (int r = 0; r < 4; ++r) {
        const float* xr = x + ((size_t)(b * LSEQ + l0 + r)) * D;
        float4 a0 = *(const float4*)(xr + i0);
        float4 a1 = *(const float4*)(xr + i0 + 4);
        float xv[8] = {a0.x, a0.y, a0.z, a0.w, a1.x, a1.y, a1.z, a1.w};
        float s0 = 0.f;
#pragma unroll
        for (int j = 0; j < 8; ++j) { s0 += xv[j] * xv[j]; xw[r][j] = xv[j] * wv[j]; }
        ss[r] = s0;
    }
    float acc[NSLOT][4];
#pragma unroll
    for (int s = 0; s < NSLOT; ++s) {
        const float* cwr = cw + (size_t)s * D + i0;
        float4 c0 = *(const float4*)(cwr);
        float4 c1 = *(const float4*)(cwr + 4);
#pragma unroll
        for (int r = 0; r < 4; ++r)
            acc[s][r] = xw[r][0] * c0.x + xw[r][1] * c0.y + xw[r][2] * c0.z + xw[r][3] * c0.w +
                        xw[r][4] * c1.x + xw[r][5] * c1.y + xw[r][6] * c1.z + xw[r][7] * c1.w;
    }
#pragma unroll
    for (int r = 0; r < 4; ++r) ss[r] = wave_sum(ss[r]);
#pragma unroll
    for (int s = 0; s < NSLOT; ++s)
#pragma unroll
        for (int r = 0; r < 4; ++r) acc[s][r] = wave_sum(acc[s][r]);
    __shared__ float red[4][NSLOT][4];
    __shared__ float redss[4][4];
    int lane = tid & 63, w = tid >> 6;
    if (lane == 0) {
#pragma unroll
        for (int r = 0; r < 4; ++r) redss[w][r] = ss[r];
#pragma unroll
        for (int s = 0; s < NSLOT; ++s)
#pragma unroll
            for (int r = 0; r < 4; ++r) red[w][s][r] = acc[s][r];
    }
    __syncthreads();
    if (tid < 64) {
        int s = tid >> 2, r = tid & 3;
        float tot = red[0][s][r] + red[1][s][r] + red[2][s][r] + red[3][s][r];
        float s2 = redss[0][r] + redss[1][r] + redss[2][r] + redss[3][r];
        float rsq = 1.0f / sqrtf(s2 * (1.0f / (float)D) + EPSV);
        logits_t[((size_t)(b * NSLOT + s)) * LSEQ + l0 + r] = tot * rsq + cb[s];
    }
}

// ---------------- top-4 + softmax + weighted row gather (xbar, bf16) ----------------
__global__ __launch_bounds__(256) void topk_xbar_kernel(
    const float* __restrict__ logits_t, const float* __restrict__ x,
    ushort* __restrict__ xbar_b) {
    int bs = blockIdx.x;
    int b = bs >> 4;
    const float* lr = logits_t + (size_t)bs * LSEQ;
    int tid = threadIdx.x, lane = tid & 63, w = tid >> 6;
    __shared__ float rv[4];
    __shared__ int ri[4];
    __shared__ float selv[4];
    __shared__ int seli[4];
    int i0 = tid * 8;
    float myv[8];
#pragma unroll
    for (int j = 0; j < 8; ++j) myv[j] = lr[i0 + j];
    int chosen[4];
    for (int p = 0; p < 4; ++p) {
        float bv = -3.4e38f;
        int bi = 0x7fffffff;
#pragma unroll
        for (int j = 0; j < 8; ++j) {
            int i = i0 + j;
            bool skip = false;
            for (int q = 0; q < p; ++q) skip = skip || (i == chosen[q]);
            float v = myv[j];
            if (!skip && (v > bv || (v == bv && i < bi))) { bv = v; bi = i; }
        }
#pragma unroll
        for (int off = 1; off < 64; off <<= 1) {
            float ov = __shfl_xor(bv, off, 64);
            int oi = __shfl_xor(bi, off, 64);
            if (ov > bv || (ov == bv && oi < bi)) { bv = ov; bi = oi; }
        }
        if (lane == 0) { rv[w] = bv; ri[w] = bi; }
        __syncthreads();
        if (tid == 0) {
            float fv = rv[0];
            int fi = ri[0];
            for (int q = 1; q < 4; ++q)
                if (rv[q] > fv || (rv[q] == fv && ri[q] < fi)) { fv = rv[q]; fi = ri[q]; }
            selv[p] = fv;
            seli[p] = fi;
        }
        __syncthreads();
        chosen[p] = seli[p];
    }
    float vals[4];
#pragma unroll
    for (int p = 0; p < 4; ++p) vals[p] = selv[p];
    float mx = vals[0];   // first pick is the max
    float e[4], den = 0.f;
#pragma unroll
    for (int p = 0; p < 4; ++p) { e[p] = expf(vals[p] - mx); den += e[p]; }
    float inv = 1.0f / den;
    const float* xr0 = x + ((size_t)b * LSEQ + chosen[0]) * D;
    const float* xr1 = x + ((size_t)b * LSEQ + chosen[1]) * D;
    const float* xr2 = x + ((size_t)b * LSEQ + chosen[2]) * D;
    const float* xr3 = x + ((size_t)b * LSEQ + chosen[3]) * D;
    float s[8];
#pragma unroll
    for (int j = 0; j < 8; ++j) {
        int i = i0 + j;
        s[j] = (e[0] * xr0[i] + e[1] * xr1[i] + e[2] * xr2[i] + e[3] * xr3[i]) * inv;
    }
    uint4 o;
    o.x = (uint)f2bf(s[0]) | ((uint)f2bf(s[1]) << 16);
    o.y = (uint)f2bf(s[2]) | ((uint)f2bf(s[3]) << 16);
    o.z = (uint)f2bf(s[4]) | ((uint)f2bf(s[5]) << 16);
    o.w = (uint)f2bf(s[6]) | ((uint)f2bf(s[7]) << 16);
    *(uint4*)(xbar_b + (size_t)bs * D + i0) = o;
}

// ---------------- ws = rms(ws_prev + written) (+bf16 copy) ----------------
__global__ __launch_bounds__(256) void ws_update_kernel(
    const float* __restrict__ written, const float* __restrict__ ws_prev,
    const float* __restrict__ workspace0, int first,
    const float* __restrict__ wpost, float* __restrict__ ws_out,
    ushort* __restrict__ ws_b) {
    int bs = blockIdx.x;
    int s = bs & (NSLOT - 1);
    int tid = threadIdx.x;
    int i0 = tid * 8;
    const float* prev = first ? (workspace0 + (size_t)s * D) : (ws_prev + (size_t)bs * D);
    const float* wr = written + (size_t)bs * D;
    float4 p0 = *(const float4*)(prev + i0);
    float4 p1 = *(const float4*)(prev + i0 + 4);
    float4 q0 = *(const float4*)(wr + i0);
    float4 q1 = *(const float4*)(wr + i0 + 4);
    float t[8] = {p0.x + q0.x, p0.y + q0.y, p0.z + q0.z, p0.w + q0.w,
                  p1.x + q1.x, p1.y + q1.y, p1.z + q1.z, p1.w + q1.w};
    float ss = 0.f;
#pragma unroll
    for (int j = 0; j < 8; ++j) ss += t[j] * t[j];
    ss = wave_sum(ss);
    __shared__ float sb[4];
    if ((tid & 63) == 0) sb[tid >> 6] = ss;
    __syncthreads();
    ss = sb[0] + sb[1] + sb[2] + sb[3];
    float rsq = 1.0f / sqrtf(ss * (1.0f / (float)D) + EPSV);
    float4 w0 = *(const float4*)(wpost + i0);
    float4 w1 = *(const float4*)(wpost + i0 + 4);
    float wv[8] = {w0.x, w0.y, w0.z, w0.w, w1.x, w1.y, w1.z, w1.w};
    float o[8];
#pragma unroll
    for (int j = 0; j < 8; ++j) o[j] = t[j] * rsq * wv[j];
    float4 r0 = {o[0], o[1], o[2], o[3]};
    float4 r1 = {o[4], o[5], o[6], o[7]};
    *(float4*)(ws_out + (size_t)bs * D + i0) = r0;
    *(float4*)(ws_out + (size_t)bs * D + i0 + 4) = r1;
    uint4 ob;
    ob.x = (uint)f2bf(o[0]) | ((uint)f2bf(o[1]) << 16);
    ob.y = (uint)f2bf(o[2]) | ((uint)f2bf(o[3]) << 16);
    ob.z = (uint)f2bf(o[4]) | ((uint)f2bf(o[5]) << 16);
    ob.w = (uint)f2bf(o[6]) | ((uint)f2bf(o[7]) << 16);
    *(uint4*)(ws_b + (size_t)bs * D + i0) = ob;
}

// ---------------- x = rms(x + attn_out) (+bf16 copy) ----------------
__global__ __launch_bounds__(256) void resid_rms_kernel(
    const float* __restrict__ x_src, const float* __restrict__ ao,
    const float* __restrict__ wpost, float* __restrict__ x_dst,
    ushort* __restrict__ xb) {
    int row = blockIdx.x;
    int tid = threadIdx.x;
    int i0 = tid * 8;
    const float* xr = x_src + (size_t)row * D;
    const float* ar = ao + (size_t)row * D;
    float4 p0 = *(const float4*)(xr + i0);
    float4 p1 = *(const float4*)(xr + i0 + 4);
    float4 q0 = *(const float4*)(ar + i0);
    float4 q1 = *(const float4*)(ar + i0 + 4);
    float t[8] = {p0.x + q0.x, p0.y + q0.y, p0.z + q0.z, p0.w + q0.w,
                  p1.x + q1.x, p1.y + q1.y, p1.z + q1.z, p1.w + q1.w};
    float ss = 0.f;
#pragma unroll
    for (int j = 0; j < 8; ++j) ss += t[j] * t[j];
    ss = wave_sum(ss);
    __shared__ float sb[4];
    if ((tid & 63) == 0) sb[tid >> 6] = ss;
    __syncthreads();
    ss = sb[0] + sb[1] + sb[2] + sb[3];
    float rsq = 1.0f / sqrtf(ss * (1.0f / (float)D) + EPSV);
    float4 w0 = *(const float4*)(wpost + i0);
    float4 w1 = *(const float4*)(wpost + i0 + 4);
    float wv[8] = {w0.x, w0.y, w0.z, w0.w, w1.x, w1.y, w1.z, w1.w};
    float o[8];
#pragma unroll
    for (int j = 0; j < 8; ++j) o[j] = t[j] * rsq * wv[j];
    float4 r0 = {o[0], o[1], o[2], o[3]};
    float4 r1 = {o[4], o[5], o[6], o[7]};
    *(float4*)(x_dst + (size_t)row * D + i0) = r0;
    *(float4*)(x_dst + (size_t)row * D + i0 + 4) = r1;
    uint4 ob;
    ob.x = (uint)f2bf(o[0]) | ((uint)f2bf(o[1]) << 16);
    ob.y = (uint)f2bf(o[2]) | ((uint)f2bf(o[3]) << 16);
    ob.z = (uint)f2bf(o[4]) | ((uint)f2bf(o[5]) << 16);
    ob.w = (uint)f2bf(o[6]) | ((uint)f2bf(o[7]) << 16);
    *(uint4*)(xb + (size_t)row * D + i0) = ob;
}

// ---------------- kv repack: kvbuf f32 [b,s,2D] -> kb/vb bf16 [b,h,s,64] --------
__global__ __launch_bounds__(256) void kv_repack_kernel(
    const float* __restrict__ kv, ushort* __restrict__ kb, ushort* __restrict__ vb) {
    int bs = blockIdx.x;                // b*16+s
    int b = bs >> 4, s = bs & 15;
    int t = threadIdx.x;
    int dg = t * 8;                     // global d in [0,2048)
    int h = dg >> 6, d = dg & 63;
    const float* kp = kv + (size_t)bs * (2 * D) + dg;
    float4 k0 = *(const float4*)kp;
    float4 k1 = *(const float4*)(kp + 4);
    float4 v0 = *(const float4*)(kp + D);
    float4 v1 = *(const float4*)(kp + D + 4);
    uint4 ko, vo;
    ko.x = (uint)f2bf(k0.x) | ((uint)f2bf(k0.y) << 16);
    ko.y = (uint)f2bf(k0.z) | ((uint)f2bf(k0.w) << 16);
    ko.z = (uint)f2bf(k1.x) | ((uint)f2bf(k1.y) << 16);
    ko.w = (uint)f2bf(k1.z) | ((uint)f2bf(k1.w) << 16);
    vo.x = (uint)f2bf(v0.x) | ((uint)f2bf(v0.y) << 16);
    vo.y = (uint)f2bf(v0.z) | ((uint)f2bf(v0.w) << 16);
    vo.z = (uint)f2bf(v1.x) | ((uint)f2bf(v1.y) << 16);
    vo.w = (uint)f2bf(v1.z) | ((uint)f2bf(v1.w) << 16);
    size_t dst = (((size_t)(b * NHEAD + h)) * NSLOT + s) * HDIM + d;
    *(uint4*)(kb + dst) = ko;
    *(uint4*)(vb + dst) = vo;
}

// ---------------- attention v6: 8 lanes per row, registers only ----------------
// No LDS, no barriers. Lane group of 8 owns one (b,h,l) row; each lane one
// 8-wide d-chunk. 3-stage shfl_xor butterfly (1,2,4) reduces the 16 slot dots
// within the group; softmax computed per-thread (redundant x8). Fully coalesced
// q read / ctx write (8 x 128B lines per wave). 2M threads -> pure TLP.
__global__ __launch_bounds__(256) void attn_kernel(
    const ushort* __restrict__ qb, const ushort* __restrict__ kb,
    const ushort* __restrict__ vb, ushort* __restrict__ ctxb) {
    int g = blockIdx.x * 256 + threadIdx.x;
    int w = g >> 6;                     // global wave id
    int lane = g & 63;
    int b = w >> 13;                    // 8192 waves per batch
    int h = (w >> 8) & 31;
    int lt = w & 255;
    int l = lt * 8 + (lane >> 3);
    int d0 = (lane & 7) * 8;
    // q row chunk
    uint4 qv = *(const uint4*)(qb + ((size_t)(b * LSEQ + l)) * D + h * HDIM + d0);
    float qf[8];
    qf[0] = __uint_as_float(qv.x << 16);
    qf[1] = __uint_as_float(qv.x & 0xffff0000u);
    qf[2] = __uint_as_float(qv.y << 16);
    qf[3] = __uint_as_float(qv.y & 0xffff0000u);
    qf[4] = __uint_as_float(qv.z << 16);
    qf[5] = __uint_as_float(qv.z & 0xffff0000u);
    qf[6] = __uint_as_float(qv.w << 16);
    qf[7] = __uint_as_float(qv.w & 0xffff0000u);
    const ushort* kbase = kb + (((size_t)(b * NHEAD + h)) * NSLOT) * HDIM + d0;
    float p[NSLOT];
#pragma unroll
    for (int s = 0; s < NSLOT; ++s) {
        uint4 kc = *(const uint4*)(kbase + s * HDIM);
        float a;
        a  = qf[0] * __uint_as_float(kc.x << 16);
        a += qf[1] * __uint_as_float(kc.x & 0xffff0000u);
        a += qf[2] * __uint_as_float(kc.y << 16);
        a += qf[3] * __uint_as_float(kc.y & 0xffff0000u);
        a += qf[4] * __uint_as_float(kc.z << 16);
        a += qf[5] * __uint_as_float(kc.z & 0xffff0000u);
        a += qf[6] * __uint_as_float(kc.w << 16);
        a += qf[7] * __uint_as_float(kc.w & 0xffff0000u);
        p[s] = a;
    }
    // butterfly reduce within 8-lane group -> all lanes hold full dots
#pragma unroll
    for (int s = 0; s < NSLOT; ++s) {
        float v = p[s];
        v += __shfl_xor(v, 1, 64);
        v += __shfl_xor(v, 2, 64);
        v += __shfl_xor(v, 4, 64);
        p[s] = v;
    }
    float mx = p[0];
#pragma unroll
    for (int s = 1; s < NSLOT; ++s) mx = fmaxf(mx, p[s]);
    float den = 0.f;
#pragma unroll
    for (int s = 0; s < NSLOT; ++s) { p[s] = __expf((p[s] - mx) * 0.125f); den += p[s]; }
    float inv = 1.0f / den;
#pragma unroll
    for (int s = 0; s < NSLOT; ++s) p[s] *= inv;
    // PV on own chunk
    const ushort* vbase = vb + (((size_t)(b * NHEAD + h)) * NSLOT) * HDIM + d0;
    float cx[8] = {0.f, 0.f, 0.f, 0.f, 0.f, 0.f, 0.f, 0.f};
#pragma unroll
    for (int s = 0; s < NSLOT; ++s) {
        uint4 vc = *(const uint4*)(vbase + s * HDIM);
        float es = p[s];
        cx[0] += es * __uint_as_float(vc.x << 16);
        cx[1] += es * __uint_as_float(vc.x & 0xffff0000u);
        cx[2] += es * __uint_as_float(vc.y << 16);
        cx[3] += es * __uint_as_float(vc.y & 0xffff0000u);
        cx[4] += es * __uint_as_float(vc.z << 16);
        cx[5] += es * __uint_as_float(vc.z & 0xffff0000u);
        cx[6] += es * __uint_as_float(vc.w << 16);
        cx[7] += es * __uint_as_float(vc.w & 0xffff0000u);
    }
    uint4 o;
    o.x = (uint)f2bf(cx[0]) | ((uint)f2bf(cx[1]) << 16);
    o.y = (uint)f2bf(cx[2]) | ((uint)f2bf(cx[3]) << 16);
    o.z = (uint)f2bf(cx[4]) | ((uint)f2bf(cx[5]) << 16);
    o.w = (uint)f2bf(cx[6]) | ((uint)f2bf(cx[7]) << 16);
    *(uint4*)(ctxb + ((size_t)(b * LSEQ + l)) * D + h * HDIM + d0) = o;
}

// ---------------- small-M bf16 MFMA GEMM (M<=128 rows) ----------------
template <int BM>
__global__ __launch_bounds__(256) void gemm_bt(
    const ushort* __restrict__ A, const ushort* __restrict__ Bw,
    const float* __restrict__ bias, float* __restrict__ C,
    int M, int N, int K) {
    constexpr int BN = 128, BK = 32;
    constexpr int MF = BM / 32;
    constexpr int APASS = (BM * BK / 8) / 256;
    __shared__ short lds[2][(BM + BN) * BK];
    int tid = threadIdx.x;
    int lane = tid & 63, w = tid >> 6;
    int wr = w >> 1, wc = w & 1;
    int tn = blockIdx.x * BN;
    int tm = blockIdx.y * BM;
    f32x4 acc[MF][4];
    f32x4 zero = {0.f, 0.f, 0.f, 0.f};
#pragma unroll
    for (int m = 0; m < MF; ++m)
#pragma unroll
        for (int n = 0; n < 4; ++n) acc[m][n] = zero;
    int NT = K / BK;

    auto stage = [&](int buf, int t) {
        int kt = t * BK;
#pragma unroll
        for (int p = 0; p < APASS; ++p) {
            int cb = p * 256 + w * 64;
            int c = cb + lane;
            int r = c >> 2;
            int k8 = (c & 3) * 8;
            int gr = tm + r;
            if (gr >= M) gr = M - 1;
            gl_lds16(A + (size_t)gr * K + kt + k8, (void*)&lds[buf][cb * 8]);
        }
#pragma unroll
        for (int p = 0; p < 2; ++p) {
            int cb = p * 256 + w * 64;
            int c = cb + lane;
            int r = c >> 2;
            int k8 = (c & 3) * 8;
            gl_lds16(Bw + (size_t)(tn + r) * K + kt + k8,
                     (void*)&lds[buf][BM * BK + cb * 8]);
        }
    };
    stage(0, 0);
    for (int t = 0; t < NT; ++t) {
        __syncthreads();
        if (t + 1 < NT) stage((t + 1) & 1, t + 1);
        const short* Ab = &lds[t & 1][0];
        const short* Bb = &lds[t & 1][BM * BK];
        int ko = (lane >> 4) * 8;
        int rr = lane & 15;
        bf16x8 af[MF], bfr[4];
#pragma unroll
        for (int m = 0; m < MF; ++m)
            af[m] = *(const bf16x8*)&Ab[(wr * (MF * 16) + m * 16 + rr) * BK + ko];
#pragma unroll
        for (int n = 0; n < 4; ++n)
            bfr[n] = *(const bf16x8*)&Bb[(wc * 64 + n * 16 + rr) * BK + ko];
#pragma unroll
        for (int m = 0; m < MF; ++m)
#pragma unroll
            for (int n = 0; n < 4; ++n)
                acc[m][n] = __builtin_amdgcn_mfma_f32_16x16x32_bf16(af[m], bfr[n],
                                                                    acc[m][n], 0, 0, 0);
    }
#pragma unroll
    for (int m = 0; m < MF; ++m) {
#pragma unroll
        for (int n = 0; n < 4; ++n) {
            int col = tn + wc * 64 + n * 16 + (lane & 15);
            float bsv = bias ? bias[col] : 0.f;
#pragma unroll
            for (int r = 0; r < 4; ++r) {
                int rowi = tm + wr * (MF * 16) + m * 16 + (lane >> 4) * 4 + r;
                if (rowi < M) C[(size_t)rowi * N + col] = acc[m][n][r] + bsv;
            }
        }
    }
}

// ---------------- big GEMM: 256x256 tile, BK=64, 8 waves, counted vmcnt ----------------
template <typename OT>
__global__ __launch_bounds__(512, 2) void gemm_big(
    const ushort* __restrict__ A, const ushort* __restrict__ Bw,
    const float* __restrict__ bias, OT* __restrict__ C,
    int M, int N, int K) {
    __shared__ ushort Al[2][256 * 64];   // 64 KiB
    __shared__ ushort Bl[2][256 * 64];   // 64 KiB
    int blk = blockIdx.x;
    int bn = blk & 7;                    // same-XCD blocks share B panel (L2)
    int bm = blk >> 3;
    int tid = threadIdx.x;
    int lane = tid & 63, wv = tid >> 6;
    int wm = wv >> 2, wn = wv & 3;       // 2 x 4 wave grid -> 128x64 per wave
    int rr = lane & 15, ko = lane >> 4;  // frag row, k-octet 0..3
    const size_t rowA0 = (size_t)bm * 256;
    const size_t rowB0 = (size_t)bn * 256;

    auto stage = [&](int buf, int t) {
        int kt = t * 64;
#pragma unroll
        for (int p = 0; p < 4; ++p) {
            int cb = p * 512 + wv * 64;          // wave-uniform chunk base
            int ch = cb + lane;
            int r = ch >> 3;
            int cl = (ch & 7) ^ (r & 7);         // pre-swizzled source chunk
            gl_lds16(A + (rowA0 + r) * K + kt + cl * 8,
                     (void*)((char*)&Al[buf][0] + cb * 16));
        }
#pragma unroll
        for (int p = 0; p < 4; ++p) {
            int cb = p * 512 + wv * 64;
            int ch = cb + lane;
            int r = ch >> 3;
            int cl = (ch & 7) ^ (r & 7);
            gl_lds16(Bw + (rowB0 + r) * K + kt + cl * 8,
                     (void*)((char*)&Bl[buf][0] + cb * 16));
        }
    };

    f32x4 acc[8][4];
    f32x4 zero = {0.f, 0.f, 0.f, 0.f};
#pragma unroll
    for (int m = 0; m < 8; ++m)
#pragma unroll
        for (int n = 0; n < 4; ++n) acc[m][n] = zero;

    int NT = K / 64;
    stage(0, 0);
    stage(1, 1);
    for (int t = 0; t < NT; ++t) {
        // wait for THIS tile's 8 loads (t+1's 8 may stay in flight)
        if (t + 2 <= NT) asm volatile("s_waitcnt vmcnt(8)" ::: "memory");
        else             asm volatile("s_waitcnt vmcnt(0)" ::: "memory");
        asm volatile("s_barrier" ::: "memory");   // all waves' tile-t loads landed
        const ushort* Ab = &Al[t & 1][0];
        const ushort* Bb = &Bl[t & 1][0];
        bf16x8 bfr[4][2];
#pragma unroll
        for (int n = 0; n < 4; ++n)
#pragma unroll
            for (int ks = 0; ks < 2; ++ks) {
                int r = wn * 64 + n * 16 + rr;
                int cl = ks * 4 + ko;
                bfr[n][ks] = *(const bf16x8*)((const char*)Bb + r * 128 +
                                              ((cl ^ (r & 7)) * 16));
            }
        __builtin_amdgcn_s_setprio(1);
#pragma unroll
        for (int m = 0; m < 8; ++m) {
            int r = wm * 128 + m * 16 + rr;
            bf16x8 a0 = *(const bf16x8*)((const char*)Ab + r * 128 +
                                         (((0 + ko) ^ (r & 7)) * 16));
            bf16x8 a1 = *(const bf16x8*)((const char*)Ab + r * 128 +
                                         (((4 + ko) ^ (r & 7)) * 16));
#pragma unroll
            for (int n = 0; n < 4; ++n) {
                acc[m][n] = __builtin_amdgcn_mfma_f32_16x16x32_bf16(a0, bfr[n][0],
                                                                    acc[m][n], 0, 0, 0);
                acc[m][n] = __builtin_amdgcn_mfma_f32_16x16x32_bf16(a1, bfr[n][1],
                                                                    acc[m][n], 0, 0, 0);
            }
        }
        __builtin_amdgcn_s_setprio(0);
        asm volatile("s_barrier" ::: "memory");   // all waves done reading buf[t&1]
        if (t + 2 < NT) stage(t & 1, t + 2);      // overwrite just-consumed buffer
    }
    int crow0 = (int)rowA0 + wm * 128;
    int ccol0 = bn * 256 + wn * 64;
#pragma unroll
    for (int m = 0; m < 8; ++m)
#pragma unroll
        for (int n = 0; n < 4; ++n) {
            int col = ccol0 + n * 16 + rr;
            float bsv = bias ? bias[col] : 0.f;
#pragma unroll
            for (int r4 = 0; r4 < 4; ++r4) {
                int row = crow0 + m * 16 + ko * 4 + r4;
                float v = acc[m][n][r4] + bsv;
                if constexpr (sizeof(OT) == 2) {
                    ((ushort*)C)[(size_t)row * N + col] = f2bf(v);
                } else {
                    ((float*)C)[(size_t)row * N + col] = v;
                }
            }
        }
}

extern "C" void kernel_launch(void* const* d_in, const int* in_sizes, int n_in,
                              void* d_out, int out_size, void* d_ws, size_t ws_size,
                              hipStream_t stream) {
    const float* x_in       = (const float*)d_in[0];
    const float* workspace  = (const float*)d_in[1];
    const float* compete_w  = (const float*)d_in[2];
    const float* compete_b  = (const float*)d_in[3];
    const float* write_w    = (const float*)d_in[4];
    const float* write_b    = (const float*)d_in[5];
    const float* in_proj_w  = (const float*)d_in[6];
    const float* in_proj_b  = (const float*)d_in[7];
    const float* out_proj_w = (const float*)d_in[8];
    const float* out_proj_b = (const float*)d_in[9];
    const float* norm_pre_w  = (const float*)d_in[12];
    const float* norm_post_w = (const float*)d_in[13];
    float* xout = (float*)d_out;

    char* base = (char*)d_ws;
    size_t off = 0;
    auto alloc = [&](size_t bytes) {
        void* p = base + off;
        off += (bytes + 255) & ~(size_t)255;
        return p;
    };
    ushort* xb      = (ushort*)alloc((size_t)BL * D * 2);
    float*  qbuf    = (float*) alloc((size_t)BL * D * 4);     // attn_out (f32)
    ushort* qbb     = (ushort*)alloc((size_t)BL * D * 2);     // q bf16
    ushort* ctxb    = (ushort*)alloc((size_t)BL * D * 2);
    float*  logits  = (float*) alloc((size_t)BATCH * NSLOT * LSEQ * 4);
    ushort* xbar    = (ushort*)alloc((size_t)BATCH * NSLOT * D * 2);
    float*  written = (float*) alloc((size_t)BATCH * NSLOT * D * 4);
    float*  wsbuf   = (float*) alloc((size_t)BATCH * NSLOT * D * 4);
    ushort* wsb     = (ushort*)alloc((size_t)BATCH * NSLOT * D * 2);
    float*  kvbuf   = (float*) alloc((size_t)BATCH * NSLOT * 2 * D * 4);
    ushort* ipb     = (ushort*)alloc((size_t)3 * D * D * 2);
    ushort* wob     = (ushort*)alloc((size_t)D * D * 2);
    ushort* wwb     = (ushort*)alloc((size_t)D * D * 2);
    ushort* kb16    = (ushort*)alloc((size_t)BATCH * NHEAD * NSLOT * HDIM * 2);
    ushort* vb16    = (ushort*)alloc((size_t)BATCH * NHEAD * NSLOT * HDIM * 2);
    (void)ws_size; (void)in_sizes; (void)n_in; (void)out_size;

    conv_bf16_kernel<<<2048, 256, 0, stream>>>((const float4*)in_proj_w, ipb, 3 * D * D / 4);
    conv_bf16_kernel<<<2048, 256, 0, stream>>>((const float4*)out_proj_w, wob, D * D / 4);
    conv_bf16_kernel<<<2048, 256, 0, stream>>>((const float4*)write_w, wwb, D * D / 4);
    conv_bf16_kernel<<<2048, 256, 0, stream>>>((const float4*)x_in, xb, BL * D / 4);

    for (int it = 0; it < 2; ++it) {
        const float* xs = it ? (const float*)xout : x_in;
        logits_kernel<<<BL / 4, 256, 0, stream>>>(xs, compete_w, compete_b, norm_pre_w,
                                                  logits);
        topk_xbar_kernel<<<BATCH * NSLOT, 256, 0, stream>>>(logits, xs, xbar);
        gemm_bt<64><<<dim3(D / 128, 1), 256, 0, stream>>>(xbar, wwb, write_b, written,
                                                          BATCH * NSLOT, D, D);
        ws_update_kernel<<<BATCH * NSLOT, 256, 0, stream>>>(written, wsbuf, workspace,
                                                            it == 0 ? 1 : 0, norm_post_w,
                                                            wsbuf, wsb);
        gemm_bt<64><<<dim3(2 * D / 128, 1), 256, 0, stream>>>(wsb, ipb + (size_t)D * D,
                                                              in_proj_b + D, kvbuf,
                                                              BATCH * NSLOT, 2 * D, D);
        kv_repack_kernel<<<BATCH * NSLOT, 256, 0, stream>>>(kvbuf, kb16, vb16);
        gemm_big<ushort><<<(D / 256) * (BL / 256), 512, 0, stream>>>(xb, ipb, in_proj_b,
                                                                     qbb, BL, D, D);
        attn_kernel<<<BL * NHEAD * 8 / 256, 256, 0, stream>>>(qbb, kb16, vb16, ctxb);
        gemm_big<float><<<(D / 256) * (BL / 256), 512, 0, stream>>>(ctxb, wob, out_proj_b,
                                                                    qbuf, BL, D, D);
        resid_rms_kernel<<<BL, 256, 0, stream>>>(xs, qbuf, norm_post_w, xout, xb);
    }
}